// Round 10
// baseline (189.794 us; speedup 1.0000x reference)
//
#include <hip/hip_runtime.h>

// DSQG attention, J=12 causal offsets, f32.
// R11: XCD-phase head scheduling for L2 residency. R10 post-mortem: traffic
// cut (0.79x lines) -> time FLAT; delivered BW ~4 TB/s << 34.5 TB/s L2
// ceiling => rows are served by L3 (~600-900 cy) because each XCD works 4
// heads concurrently (8 MB k/v > 4 MB L2). Fix = placement, not traffic:
//   * persistent grid of 256 blocks (1/CU; 115 KB LDS forces it anyway).
//     xcd = blockIdx&7, slot = blockIdx>>3 (0..31). 4 phases; in phase p,
//     XCD x's 32 blocks all process head bh = 4*x + p (32 chunks x 128 pos).
//     Per-XCD working set = 2 MB < 4 MB L2; +-1 phase skew still fits (4 MB).
//     Large-offset k/v reads become L2 hits (~250 cy) -> MSHR-limited fill
//     rate ~doubles (64 lines x 128 B / 250 cy ~= 32 B/cy/CU).
//   * per phase: restage LDS window, reload per-head scalars, run R10's
//     verified 4-iteration macro pipeline. Barriers bracket staging; the
//     only cross-phase vmem op (the tracked store) is OLDEST at the next
//     counted wait, so the vmcnt ledger is unchanged (conservative-safe).
// Carried from R10: 224-row k/v LDS window serves d in {1..96}; 5 large
// offsets via asm batches with counted vmcnt; lane-parallel rotation; DPP
// 16-lane allreduce; max-free softmax; v_rcp; asm-pinned scalar preloads.

namespace {

constexpr int J   = 12;
constexpr int B_  = 2;
constexpr int H_  = 16;
constexpr int N_  = 4096;
constexpr int HD_ = 64;
constexpr int OFFS[J] = {1, 2, 4, 8, 16, 64, 96, 192, 384, 512, 768, 1024};
constexpr int T_   = 128;          // positions per chunk
constexpr int HALO = 96;           // window back-reach (covers d<=96)
constexpr int W_   = T_ + HALO;    // 224 staged rows: [P-96, P+127]
constexpr int LDS_KV = W_ * 16 * 16;                 // bytes of kS (= vS)
constexpr int LDS_TOTAL = 2 * LDS_KV + J * 16 * 16;  // + seS = 117760 B

using f32x4 = __attribute__((ext_vector_type(4))) float;
using f32x2 = __attribute__((ext_vector_type(2))) float;

#define GLOAD4(dst, off, base)                                              \
    asm volatile("global_load_dwordx4 %0, %1, %2"                           \
                 : "=v"(dst) : "v"(off), "s"(base) : "memory")
#define GLOAD2(dst, off, base)                                              \
    asm volatile("global_load_dwordx2 %0, %1, %2"                           \
                 : "=v"(dst) : "v"(off), "s"(base) : "memory")

#define VMWAIT(N)                                                           \
    asm volatile("s_waitcnt vmcnt(" #N ")" ::: "memory");                   \
    __builtin_amdgcn_sched_barrier(0)

// p += dpp_mov(p); CTRL must be an ICE, hence the template.
template <int CTRL>
__device__ __forceinline__ float dpp_add(float x) {
    int s = __builtin_amdgcn_update_dpp(0, __builtin_bit_cast(int, x),
                                        CTRL, 0xF, 0xF, false);
    return x + __builtin_bit_cast(float, s);
}

// A-batch for position nn: q, 5 large-d k (i=7..11), y, z — 8 vmem ops in
// this exact order (vmcnt ledger depends on it).
#define ISSUEA(nn, QR, KR, YP, ZL) do {                                     \
    const int nA_ = (nn);                                                   \
    const uint32_t rbA_ = ((uint32_t)nA_ << 8) + gbl;                       \
    GLOAD4(QR, rbA_, qb);                                                   \
    _Pragma("unroll")                                                       \
    for (int i = 7; i < J; ++i) {                                           \
        const uint32_t oA_ = (nA_ >= OFFS[i])                               \
            ? (rbA_ - ((uint32_t)OFFS[i] << 8)) : gbl;                      \
        GLOAD4(KR[i - 7], oA_, kb);                                         \
    }                                                                       \
    const uint32_t nb8A_ = (uint32_t)nA_ << 3;                              \
    GLOAD2(YP, nb8A_, yb);                                                  \
    const uint32_t zoA_ = (nA_ >= dl) ? ((uint32_t)(nA_ - dl) << 3) : 0u;   \
    GLOAD2(ZL, zoA_, zb);                                                   \
} while (0)

// One pipeline iteration; TOPN/TAILN literal vmcnt counts, PREF literal 0/1.
#define ITERBODY(NVAL, TOPN, TAILN, PREF, QR, KR, YP, ZL, QRN, KRN, YPN, ZLN) \
do {                                                                        \
    const int n_ = (NVAL);                                                  \
    const uint32_t rowb_ = ((uint32_t)n_ << 8) + gbl;                       \
    VMWAIT(TOPN);                              /* q+5k of A(j) ready */     \
    const int rbase_ = n_ - P + HALO;          /* in [96, 223] */           \
    float p_[J];                                                            \
    _Pragma("unroll")                                                       \
    for (int i = 0; i < 7; ++i) {              /* d in {1..96} from LDS */  \
        const f32x4 kk  = kS[(rbase_ - OFFS[i]) * 16 + grp];                \
        const f32x4 seg = seS[i * 16 + grp];                                \
        float t = QR.x * (kk.x + seg.x);                                    \
        t = fmaf(QR.y, kk.y + seg.y, t);                                    \
        t = fmaf(QR.z, kk.z + seg.z, t);                                    \
        p_[i] = fmaf(QR.w, kk.w + seg.w, t);                                \
    }                                                                       \
    _Pragma("unroll")                                                       \
    for (int i = 7; i < J; ++i) {              /* large d from regs */      \
        const f32x4 kk  = KR[i - 7];                                        \
        const f32x4 seg = seS[i * 16 + grp];                                \
        float t = QR.x * (kk.x + seg.x);                                    \
        t = fmaf(QR.y, kk.y + seg.y, t);                                    \
        t = fmaf(QR.z, kk.z + seg.z, t);                                    \
        p_[i] = fmaf(QR.w, kk.w + seg.w, t);                                \
    }                                                                       \
    /* batch B(j): 5 large-d v + vx(global path) */                         \
    f32x4 vr_[5];                                                           \
    _Pragma("unroll")                                                       \
    for (int i = 7; i < J; ++i) {                                           \
        const uint32_t oB_ = (n_ >= OFFS[i])                                \
            ? (rowb_ - ((uint32_t)OFFS[i] << 8)) : gbl;                     \
        GLOAD4(vr_[i - 7], oB_, vb);                                        \
    }                                                                       \
    f32x4 vxg_;                                                             \
    const uint32_t vxo_ = ((t8 >= 3) && (n_ >= dl))                         \
        ? ((uint32_t)(n_ - dl) << 8) : 0u;                                  \
    GLOAD4(vxg_, vxo_, vb);                                                 \
    if (PREF) { ISSUEA(n_ + 32, QRN, KRN, YPN, ZLN); }                      \
    /* 16-lane allreduce (pure VALU DPP); covers B + A(j+1) latency */      \
    _Pragma("unroll")                                                       \
    for (int i = 0; i < J; ++i) {                                           \
        p_[i] = dpp_add<0xB1>(p_[i]);   /* quad_perm [1,0,3,2] : xor 1 */   \
        p_[i] = dpp_add<0x4E>(p_[i]);   /* quad_perm [2,3,0,1] : xor 2 */   \
        p_[i] = dpp_add<0x124>(p_[i]);  /* row_ror:4 */                     \
        p_[i] = dpp_add<0x128>(p_[i]);  /* row_ror:8 */                     \
    }                                                                       \
    float e_[J];                                                            \
    float sum_ = 0.f;                                                       \
    _Pragma("unroll")                                                       \
    for (int i = 0; i < J; ++i) {                                           \
        const float si = fmaf(p_[i], 0.125f, pbh[i]);                       \
        e_[i] = (n_ >= OFFS[i]) ? __expf(si) : 0.f;                         \
        sum_ += e_[i];                                                      \
    }                                                                       \
    /* vx LDS path for t8<=2 (dl in {16,64,96}; rows in window) */          \
    const int relv_ = (t8 <= 2) ? (rbase_ - dl) : 0;                        \
    const f32x4 vxl_ = vS[relv_ * 16];                                      \
    VMWAIT(TAILN);                 /* iter-j vmem done; A(j+1) in flight */ \
    const f32x4 vx_ = (t8 <= 2) ? vxl_ : vxg_;                              \
    /* lane-parallel rotation: lane handles offset i = 4 + t8 */            \
    const float s01_ = (t8 & 1) ? e_[5]  : e_[4];                           \
    const float s23_ = (t8 & 1) ? e_[7]  : e_[6];                           \
    const float s45_ = (t8 & 1) ? e_[9]  : e_[8];                           \
    const float s67_ = (t8 & 1) ? e_[11] : e_[10];                          \
    const float sA_  = (t8 & 2) ? s23_ : s01_;                              \
    const float sB_  = (t8 & 2) ? s67_ : s45_;                              \
    const float esel_ = (t8 & 4) ? sB_ : sA_;                               \
    const float th0_ = fmaf(pgn.x, YP.x * ZL.x, pbs.x);                     \
    const float th1_ = fmaf(pgn.y, YP.y * ZL.y, pbs.y);                     \
    const float c0_ = __cosf(th0_), s0_ = __sinf(th0_);                     \
    const float c1_ = __cosf(th1_), s1_ = __sinf(th1_);                     \
    f32x4 cx_;                                                              \
    cx_.x = esel_ * (c0_ * vx_.x - s0_ * vx_.y);                            \
    cx_.y = esel_ * (s0_ * vx_.x + c0_ * vx_.y);                            \
    cx_.z = esel_ * (c1_ * vx_.z - s1_ * vx_.w);                            \
    cx_.w = esel_ * (s1_ * vx_.z + c1_ * vx_.w);                            \
    cx_.x = dpp_add<0xB1>(cx_.x);  cx_.y = dpp_add<0xB1>(cx_.y);            \
    cx_.z = dpp_add<0xB1>(cx_.z);  cx_.w = dpp_add<0xB1>(cx_.w);            \
    cx_.x = dpp_add<0x4E>(cx_.x);  cx_.y = dpp_add<0x4E>(cx_.y);            \
    cx_.z = dpp_add<0x4E>(cx_.z);  cx_.w = dpp_add<0x4E>(cx_.w);            \
    cx_.x = dpp_add<0x124>(cx_.x); cx_.y = dpp_add<0x124>(cx_.y);           \
    cx_.z = dpp_add<0x124>(cx_.z); cx_.w = dpp_add<0x124>(cx_.w);           \
    /* weighted sum: i<7 from LDS window, i>=7 from regs */                 \
    float4 accl_ = make_float4(0.f, 0.f, 0.f, 0.f);                         \
    _Pragma("unroll")                                                       \
    for (int i = 0; i < 4; ++i) {                                           \
        const f32x4 vv = vS[(rbase_ - OFFS[i]) * 16 + grp];                 \
        accl_.x = fmaf(e_[i], vv.x, accl_.x);                               \
        accl_.y = fmaf(e_[i], vv.y, accl_.y);                               \
        accl_.z = fmaf(e_[i], vv.z, accl_.z);                               \
        accl_.w = fmaf(e_[i], vv.w, accl_.w);                               \
    }                                                                       \
    float4 acch_ = accl_;                                                   \
    _Pragma("unroll")                                                       \
    for (int i = 4; i < 7; ++i) {              /* d = 16, 64, 96 (LDS) */   \
        const f32x4 vv = vS[(rbase_ - OFFS[i]) * 16 + grp];                 \
        acch_.x = fmaf(e_[i], vv.x, acch_.x);                               \
        acch_.y = fmaf(e_[i], vv.y, acch_.y);                               \
        acch_.z = fmaf(e_[i], vv.z, acch_.z);                               \
        acch_.w = fmaf(e_[i], vv.w, acch_.w);                               \
    }                                                                       \
    _Pragma("unroll")                                                       \
    for (int i = 7; i < J; ++i) {                                           \
        acch_.x = fmaf(e_[i], vr_[i - 7].x, acch_.x);                       \
        acch_.y = fmaf(e_[i], vr_[i - 7].y, acch_.y);                       \
        acch_.z = fmaf(e_[i], vr_[i - 7].z, acch_.z);                       \
        acch_.w = fmaf(e_[i], vr_[i - 7].w, acch_.w);                       \
    }                                                                       \
    const bool lo_ = (grp == 0);                                            \
    float4 acc_;                                                            \
    acc_.x = lo_ ? accl_.x + cx_.x : acch_.x;                               \
    acc_.y = lo_ ? accl_.y + cx_.y : acch_.y;                               \
    acc_.z = lo_ ? accl_.z + cx_.z : acch_.z;                               \
    acc_.w = lo_ ? accl_.w + cx_.w : acch_.w;                               \
    float4 res_;                                                            \
    if (n_ >= 1) {                                                          \
        const float inv_ = __builtin_amdgcn_rcpf(sum_);                     \
        res_ = make_float4(acc_.x * inv_, acc_.y * inv_,                    \
                           acc_.z * inv_, acc_.w * inv_);                   \
    } else {                                                                \
        res_ = make_float4(0.f, 0.f, 0.f, 0.f);                             \
    }                                                                       \
    *(float4*)(ob + rowb_) = res_;   /* newest vmem op; bound by asm */     \
} while (0)

__global__ __launch_bounds__(512, 1) void dsqg_kernel(
    const float* __restrict__ q, const float* __restrict__ k,
    const float* __restrict__ v, const float* __restrict__ pb,
    const float* __restrict__ se, const float* __restrict__ phase_base,
    const float* __restrict__ phase_gain, const float* __restrict__ y_pre,
    const float* __restrict__ z_pre, float* __restrict__ out)
{
    extern __shared__ char smem[];
    f32x4* kS  = (f32x4*)smem;                        // 224 rows x 16 f32x4
    f32x4* vS  = (f32x4*)(smem + LDS_KV);             // 224 rows x 16 f32x4
    f32x4* seS = (f32x4*)(smem + 2 * LDS_KV);         // 12 x 16 f32x4

    // persistent mapping: 256 blocks, 1/CU. xcd gets 32 blocks (its 32 CUs);
    // in phase p those 32 blocks cover head bh = 4*xcd + p (32 x 128 pos).
    const int raw  = blockIdx.x;
    const int xcd  = raw & 7;
    const int slot = raw >> 3;                 // 0..31

    const int tid  = threadIdx.x;
    const int lane = tid & 63;
    const int wave = tid >> 6;                 // 0..7
    const int grp  = lane & 15;                // lane within position group
    const int sub  = lane >> 4;                // position-within-quad

    if (tid < J * 16) seS[tid] = ((const f32x4*)se)[tid];  // once; read-only

    // per-lane rotation offset dl = OFFS[4 + (grp&7)] via cndmask tree
    const int t8  = grp & 7;
    const int d01 = (t8 & 1) ? 64   : 16;
    const int d23 = (t8 & 1) ? 192  : 96;
    const int d45 = (t8 & 1) ? 512  : 384;
    const int d67 = (t8 & 1) ? 1024 : 768;
    const int dA  = (t8 & 2) ? d23 : d01;
    const int dB  = (t8 & 2) ? d67 : d45;
    const int dl  = (t8 & 4) ? dB : dA;

    const uint32_t gbl = (uint32_t)grp << 4;
    const int P = slot * T_;                   // chunk start (same all phases)

#pragma unroll 1
    for (int phase = 0; phase < 4; ++phase) {
        const int bh = xcd * 4 + phase;        // this XCD's head this phase
        const int h  = bh & (H_ - 1);

        // uniform (SGPR) per-(b,h) base pointers
        const size_t bhbytes = (size_t)bh * (N_ * HD_ * 4);
        const char* qb = (const char*)q + bhbytes;
        const char* kb = (const char*)k + bhbytes;
        const char* vb = (const char*)v + bhbytes;
        char*       ob = (char*)out + bhbytes;
        const char* yb = (const char*)y_pre + (size_t)bh * (N_ * 8);
        const char* zb = (const char*)z_pre + (size_t)bh * (N_ * 8);

        // ---- stage k/v window [P-96, P+127] into LDS (7 x 512 x 16 B) ------
        {
            const int r0 = P - HALO;
#pragma unroll
            for (int t = 0; t < (W_ * 16) / 512; ++t) {
                const int idx = t * 512 + tid;     // 0..3583 (float4 index)
                const int row = idx >> 4;
                const int col = idx & 15;
                int gr = r0 + row;                 // clamp for first chunks
                gr = gr < 0 ? 0 : gr;
                const uint32_t go = ((uint32_t)gr << 8) + ((uint32_t)col << 4);
                kS[idx] = *(const f32x4*)(kb + go);
                vS[idx] = *(const f32x4*)(vb + go);
            }
        }

        const uint32_t pofs = (uint32_t)(t8 * H_ + h) << 3;   // [pi][h][2]
        const f32x2 pbs = *(const f32x2*)((const char*)phase_base + pofs);
        const f32x2 pgn = *(const f32x2*)((const char*)phase_gain + pofs);
        float pbh[J];
#pragma unroll
        for (int i = 0; i < J; ++i) pbh[i] = pb[i * H_ + h];

        // force tracked loads to complete -> asm vmcnt ledger starts at 0
        asm volatile("" :: "v"(pbs.x), "v"(pbs.y), "v"(pgn.x), "v"(pgn.y));
        asm volatile("" :: "v"(pbh[0]), "v"(pbh[1]), "v"(pbh[2]), "v"(pbh[3]),
                           "v"(pbh[4]), "v"(pbh[5]), "v"(pbh[6]), "v"(pbh[7]),
                           "v"(pbh[8]), "v"(pbh[9]), "v"(pbh[10]), "v"(pbh[11]));

        __syncthreads();                       // staging (+seS) visible

        const int n0 = P + wave * 4 + sub;     // j advances by 32 positions

        f32x4 qrA, qrB;
        f32x4 krA[5], krB[5];
        f32x2 ypA, ypB, zlA, zlB;

        ISSUEA(n0, qrA, krA, ypA, zlA);

        ITERBODY(n0,      2, 8, 1, qrA, krA, ypA, zlA, qrB, krB, ypB, zlB);
        ITERBODY(n0 + 32, 3, 8, 1, qrB, krB, ypB, zlB, qrA, krA, ypA, zlA);
        ITERBODY(n0 + 64, 3, 8, 1, qrA, krA, ypA, zlA, qrB, krB, ypB, zlB);
        ITERBODY(n0 + 96, 3, 0, 0, qrB, krB, ypB, zlB, qrA, krA, ypA, zlA);

        if (phase < 3) __syncthreads();        // LDS reuse safety for restage
    }
}

} // namespace

extern "C" void kernel_launch(void* const* d_in, const int* in_sizes, int n_in,
                              void* d_out, int out_size, void* d_ws, size_t ws_size,
                              hipStream_t stream) {
    const float* q          = (const float*)d_in[0];
    const float* k          = (const float*)d_in[1];
    const float* v          = (const float*)d_in[2];
    const float* pb         = (const float*)d_in[3];
    const float* se         = (const float*)d_in[4];
    const float* phase_base = (const float*)d_in[5];
    const float* phase_gain = (const float*)d_in[6];
    const float* y_pre      = (const float*)d_in[7];
    const float* z_pre      = (const float*)d_in[8];
    float* out              = (float*)d_out;

    static bool attr_set = false;
    if (!attr_set) {
        (void)hipFuncSetAttribute((const void*)dsqg_kernel,
                                  hipFuncAttributeMaxDynamicSharedMemorySize,
                                  LDS_TOTAL);
        attr_set = true;
    }

    // 256 persistent blocks (1/CU); each covers 4 heads' chunks over 4 phases
    dsqg_kernel<<<256, 512, LDS_TOTAL, stream>>>(q, k, v, pb, se,
                                                 phase_base, phase_gain,
                                                 y_pre, z_pre, out);
}

// Round 11
// 173.614 us; speedup vs baseline: 1.0932x; 1.0932x over previous
//
#include <hip/hip_runtime.h>

// DSQG attention, J=12 causal offsets, f32.
// R12: single-wait full-cover pipeline (deferred epilogue) on the R7b/R9
// structure. R9 covered A (q,k) with a full iteration but waited B (v,...)
// only ~700 cy after issue -> one under-covered wait per iter remained.
// Restructure:
//   A(j) = q + 7 large-d k  [8 ops]  — no ping-pong: kr dies at dot(j),
//                                      then A(j+1) reuses the same regs.
//   B(j) = 7 large-d v + vx + y + z [10 ops] — ping-pong; consumed a FULL
//                                      iteration later by a deferred epilogue.
//   iter j: vmcnt(1) [forces B(j-1)+A(j); leaves store(j-2)] -> dot(j) ->
//           issue B(j) -> issue A(j+1) -> DPP+softmax(j) -> EPILOGUE(j-1).
//   One wait per iteration; every load has >= 1 iteration of cover.
// Ledger (per-wave, asm program order):
//   j=0 top: A(0)=8 outstanding           -> vmcnt(0)
//   j=1 top: B(0)10+A(1)8                 -> vmcnt(0)
//   j=2,3:   B10+A8+store1 (store newest) -> vmcnt(1)
//   final:   B(3)10+store(2)              -> vmcnt(1), then epilogue(3).
// launch_bounds(256,2): ~256-reg cap so the ~174-reg live set cannot force
// the RA to spill a pending asm "=v" dest (R8 crash mechanism).
// Carried from R7b/R9: 80-row k/v LDS window serves d in {1,2,4,8,16};
// lane-parallel rotation (lane t8 owns offset 4+t8); DPP 16-lane allreduce;
// max-free softmax; v_rcp; XCD swizzle; se table in LDS.

namespace {

constexpr int J   = 12;
constexpr int B_  = 2;
constexpr int H_  = 16;
constexpr int N_  = 4096;
constexpr int HD_ = 64;
constexpr int OFFS[J] = {1, 2, 4, 8, 16, 64, 96, 192, 384, 512, 768, 1024};
constexpr int T_  = 64;   // positions per block
constexpr int W_  = 80;   // staged rows: [P-16, P+63]

using f32x4 = __attribute__((ext_vector_type(4))) float;
using f32x2 = __attribute__((ext_vector_type(2))) float;

#define GLOAD4(dst, off, base)                                              \
    asm volatile("global_load_dwordx4 %0, %1, %2"                           \
                 : "=v"(dst) : "v"(off), "s"(base) : "memory")
#define GLOAD2(dst, off, base)                                              \
    asm volatile("global_load_dwordx2 %0, %1, %2"                           \
                 : "=v"(dst) : "v"(off), "s"(base) : "memory")

#define VMWAIT(N)                                                           \
    asm volatile("s_waitcnt vmcnt(" #N ")" ::: "memory");                   \
    __builtin_amdgcn_sched_barrier(0)

// p += dpp_mov(p); CTRL must be an ICE, hence the template.
template <int CTRL>
__device__ __forceinline__ float dpp_add(float x) {
    int s = __builtin_amdgcn_update_dpp(0, __builtin_bit_cast(int, x),
                                        CTRL, 0xF, 0xF, false);
    return x + __builtin_bit_cast(float, s);
}

// A-batch: q + 7 large-d k into the SHARED qr/kr regs. 8 vmem ops.
#define ISSUEA(nn) do {                                                     \
    const int nA_ = (nn);                                                   \
    const uint32_t rbA_ = ((uint32_t)nA_ << 8) + gbl;                       \
    GLOAD4(qr, rbA_, qb);                                                   \
    _Pragma("unroll")                                                       \
    for (int i = 5; i < J; ++i) {                                           \
        const uint32_t oA_ = (nA_ >= OFFS[i])                               \
            ? (rbA_ - ((uint32_t)OFFS[i] << 8)) : gbl;                      \
        GLOAD4(kr[i - 5], oA_, kb);                                         \
    }                                                                       \
} while (0)

// B-batch: 7 large-d v + vx + y + z into a named ping-pong set. 10 vmem ops.
#define ISSUEB(nn, VR, VX, YP, ZL) do {                                     \
    const int nB_ = (nn);                                                   \
    const uint32_t rbB_ = ((uint32_t)nB_ << 8) + gbl;                       \
    _Pragma("unroll")                                                       \
    for (int i = 5; i < J; ++i) {                                           \
        const uint32_t oB_ = (nB_ >= OFFS[i])                               \
            ? (rbB_ - ((uint32_t)OFFS[i] << 8)) : gbl;                      \
        GLOAD4(VR[i - 5], oB_, vb);                                         \
    }                                                                       \
    const uint32_t vxo_ = (nB_ >= dl) ? ((uint32_t)(nB_ - dl) << 8) : 0u;   \
    GLOAD4(VX, vxo_, vb);                                                   \
    const uint32_t nb8_ = (uint32_t)nB_ << 3;                               \
    GLOAD2(YP, nb8_, yb);                                                   \
    const uint32_t zo_ = (nB_ >= dl) ? ((uint32_t)(nB_ - dl) << 3) : 0u;    \
    GLOAD2(ZL, zo_, zb);                                                    \
} while (0)

// Dot for position nn using qr/kr + LDS smalls; fills shared p_[J].
#define DOTP(nn) do {                                                       \
    const int nD_ = (nn);                                                   \
    const int rbD_ = nD_ - P + 16;             /* in [16, 79] */            \
    _Pragma("unroll")                                                       \
    for (int i = 0; i < 5; ++i) {                                           \
        const f32x4 kk = kS[(rbD_ - OFFS[i]) * 16 + grp];                   \
        const f32x4 sg = seS[i * 16 + grp];                                 \
        float t = qr.x * (kk.x + sg.x);                                     \
        t = fmaf(qr.y, kk.y + sg.y, t);                                     \
        t = fmaf(qr.z, kk.z + sg.z, t);                                     \
        p_[i] = fmaf(qr.w, kk.w + sg.w, t);                                 \
    }                                                                       \
    _Pragma("unroll")                                                       \
    for (int i = 5; i < J; ++i) {                                           \
        const f32x4 kk = kr[i - 5];                                         \
        const f32x4 sg = seS[i * 16 + grp];                                 \
        float t = qr.x * (kk.x + sg.x);                                     \
        t = fmaf(qr.y, kk.y + sg.y, t);                                     \
        t = fmaf(qr.z, kk.z + sg.z, t);                                     \
        p_[i] = fmaf(qr.w, kk.w + sg.w, t);                                 \
    }                                                                       \
} while (0)

// DPP 16-lane allreduce of p_ + max-free softmax -> E[], SUM.
#define SOFTMAXE(nn, E, SUM) do {                                           \
    _Pragma("unroll")                                                       \
    for (int i = 0; i < J; ++i) {                                           \
        p_[i] = dpp_add<0xB1>(p_[i]);   /* quad_perm [1,0,3,2] : xor 1 */   \
        p_[i] = dpp_add<0x4E>(p_[i]);   /* quad_perm [2,3,0,1] : xor 2 */   \
        p_[i] = dpp_add<0x124>(p_[i]);  /* row_ror:4 */                     \
        p_[i] = dpp_add<0x128>(p_[i]);  /* row_ror:8 */                     \
    }                                                                       \
    SUM = 0.f;                                                              \
    _Pragma("unroll")                                                       \
    for (int i = 0; i < J; ++i) {                                           \
        const float si = fmaf(p_[i], 0.125f, pbh[i]);                       \
        E[i] = ((nn) >= OFFS[i]) ? __expf(si) : 0.f;                        \
        SUM += E[i];                                                        \
    }                                                                       \
} while (0)

// Deferred epilogue for position nn using its carried B set + E/SUM.
#define EPILOGUE(nn, VR, VX, YP, ZL, E, SUM) do {                           \
    const int nE_ = (nn);                                                   \
    const int rbE_ = nE_ - P + 16;                                          \
    const uint32_t rowbE_ = ((uint32_t)nE_ << 8) + gbl;                     \
    const float s01_ = (t8 & 1) ? E[5]  : E[4];                             \
    const float s23_ = (t8 & 1) ? E[7]  : E[6];                             \
    const float s45_ = (t8 & 1) ? E[9]  : E[8];                             \
    const float s67_ = (t8 & 1) ? E[11] : E[10];                            \
    const float sA_  = (t8 & 2) ? s23_ : s01_;                              \
    const float sB_  = (t8 & 2) ? s67_ : s45_;                              \
    const float esel_ = (t8 & 4) ? sB_ : sA_;                               \
    const float th0_ = fmaf(pgn.x, YP.x * ZL.x, pbs.x);                     \
    const float th1_ = fmaf(pgn.y, YP.y * ZL.y, pbs.y);                     \
    const float c0_ = __cosf(th0_), s0_ = __sinf(th0_);                     \
    const float c1_ = __cosf(th1_), s1_ = __sinf(th1_);                     \
    f32x4 cx_;                                                              \
    cx_.x = esel_ * (c0_ * VX.x - s0_ * VX.y);                              \
    cx_.y = esel_ * (s0_ * VX.x + c0_ * VX.y);                              \
    cx_.z = esel_ * (c1_ * VX.z - s1_ * VX.w);                              \
    cx_.w = esel_ * (s1_ * VX.z + c1_ * VX.w);                              \
    cx_.x = dpp_add<0xB1>(cx_.x);  cx_.y = dpp_add<0xB1>(cx_.y);            \
    cx_.z = dpp_add<0xB1>(cx_.z);  cx_.w = dpp_add<0xB1>(cx_.w);            \
    cx_.x = dpp_add<0x4E>(cx_.x);  cx_.y = dpp_add<0x4E>(cx_.y);            \
    cx_.z = dpp_add<0x4E>(cx_.z);  cx_.w = dpp_add<0x4E>(cx_.w);            \
    cx_.x = dpp_add<0x124>(cx_.x); cx_.y = dpp_add<0x124>(cx_.y);           \
    cx_.z = dpp_add<0x124>(cx_.z); cx_.w = dpp_add<0x124>(cx_.w);           \
    float4 accl_ = make_float4(0.f, 0.f, 0.f, 0.f);                         \
    _Pragma("unroll")                                                       \
    for (int i = 0; i < 4; ++i) {                                           \
        const f32x4 vv = vS[(rbE_ - OFFS[i]) * 16 + grp];                   \
        accl_.x = fmaf(E[i], vv.x, accl_.x);                                \
        accl_.y = fmaf(E[i], vv.y, accl_.y);                                \
        accl_.z = fmaf(E[i], vv.z, accl_.z);                                \
        accl_.w = fmaf(E[i], vv.w, accl_.w);                                \
    }                                                                       \
    float4 acch_ = accl_;                                                   \
    {   /* i = 4 (d = 16) from LDS */                                       \
        const f32x4 vv = vS[(rbE_ - 16) * 16 + grp];                        \
        acch_.x = fmaf(E[4], vv.x, acch_.x);                                \
        acch_.y = fmaf(E[4], vv.y, acch_.y);                                \
        acch_.z = fmaf(E[4], vv.z, acch_.z);                                \
        acch_.w = fmaf(E[4], vv.w, acch_.w);                                \
    }                                                                       \
    _Pragma("unroll")                                                       \
    for (int i = 5; i < J; ++i) {                                           \
        acch_.x = fmaf(E[i], VR[i - 5].x, acch_.x);                         \
        acch_.y = fmaf(E[i], VR[i - 5].y, acch_.y);                         \
        acch_.z = fmaf(E[i], VR[i - 5].z, acch_.z);                         \
        acch_.w = fmaf(E[i], VR[i - 5].w, acch_.w);                         \
    }                                                                       \
    const bool lo_ = (grp == 0);                                            \
    float4 acc_;                                                            \
    acc_.x = lo_ ? accl_.x + cx_.x : acch_.x;                               \
    acc_.y = lo_ ? accl_.y + cx_.y : acch_.y;                               \
    acc_.z = lo_ ? accl_.z + cx_.z : acch_.z;                               \
    acc_.w = lo_ ? accl_.w + cx_.w : acch_.w;                               \
    float4 res_;                                                            \
    if (nE_ >= 1) {                                                         \
        const float inv_ = __builtin_amdgcn_rcpf(SUM);                      \
        res_ = make_float4(acc_.x * inv_, acc_.y * inv_,                    \
                           acc_.z * inv_, acc_.w * inv_);                   \
    } else {                                                                \
        res_ = make_float4(0.f, 0.f, 0.f, 0.f);                             \
    }                                                                       \
    *(float4*)(ob + rowbE_) = res_;                                         \
} while (0)

__global__ __launch_bounds__(256, 2) void dsqg_kernel(
    const float* __restrict__ q, const float* __restrict__ k,
    const float* __restrict__ v, const float* __restrict__ pb,
    const float* __restrict__ se, const float* __restrict__ phase_base,
    const float* __restrict__ phase_gain, const float* __restrict__ y_pre,
    const float* __restrict__ z_pre, float* __restrict__ out)
{
    __shared__ f32x4 kS[W_ * 16];     // 20 KB: k rows [P-16, P+63]
    __shared__ f32x4 vS[W_ * 16];     // 20 KB: v rows [P-16, P+63]
    __shared__ f32x4 seS[J * 16];     //  3 KB: se fragments [i][grp]

    // XCD-locality swizzle: contiguous work range per XCD.
    const int raw = blockIdx.x;
    const int per = gridDim.x >> 3;            // 2048/8 = 256
    const int wid = (raw & 7) * per + (raw >> 3);

    const int bh  = wid >> 6;                  // 64 blocks per (b,h)
    const int blk = wid & 63;
    const int h   = bh & (H_ - 1);
    const int P   = blk * T_;                  // first position of this block

    const int tid  = threadIdx.x;
    const int lane = tid & 63;
    const int wave = tid >> 6;
    const int grp  = lane & 15;                // lane within position group
    const int sub  = lane >> 4;                // position-within-quad

    if (tid < J * 16) seS[tid] = ((const f32x4*)se)[tid];

    // uniform (SGPR) per-(b,h) base pointers
    const size_t bhbytes = (size_t)bh * (N_ * HD_ * 4);
    const char* qb = (const char*)q + bhbytes;
    const char* kb = (const char*)k + bhbytes;
    const char* vb = (const char*)v + bhbytes;
    char*       ob = (char*)out + bhbytes;
    const char* yb = (const char*)y_pre + (size_t)bh * (N_ * 8);
    const char* zb = (const char*)z_pre + (size_t)bh * (N_ * 8);

    // ---- stage k/v window into LDS (coalesced; 5 iters x 256 thr x 16 B) ----
    {
        const int r0 = P - 16;
#pragma unroll
        for (int t = 0; t < (W_ * 16) / 256; ++t) {
            const int idx = t * 256 + tid;     // 0..1279 (float4 index)
            const int row = idx >> 4;
            const int col = idx & 15;
            int gr = r0 + row;                 // clamp for block 0 only
            gr = gr < 0 ? 0 : gr;
            const uint32_t go = ((uint32_t)gr << 8) + ((uint32_t)col << 4);
            kS[idx] = *(const f32x4*)(kb + go);
            vS[idx] = *(const f32x4*)(vb + go);
        }
    }

    // per-lane rotation offset dl = OFFS[4 + (grp&7)] via cndmask tree
    const int t8  = grp & 7;
    const int d01 = (t8 & 1) ? 64   : 16;
    const int d23 = (t8 & 1) ? 192  : 96;
    const int d45 = (t8 & 1) ? 512  : 384;
    const int d67 = (t8 & 1) ? 1024 : 768;
    const int dA  = (t8 & 2) ? d23 : d01;
    const int dB  = (t8 & 2) ? d67 : d45;
    const int dl  = (t8 & 4) ? dB : dA;

    const uint32_t pofs = (uint32_t)(t8 * H_ + h) << 3;    // [pi][h][2] f32
    const f32x2 pbs = *(const f32x2*)((const char*)phase_base + pofs);
    const f32x2 pgn = *(const f32x2*)((const char*)phase_gain + pofs);
    float pbh[J];
#pragma unroll
    for (int i = 0; i < J; ++i) pbh[i] = pb[i * H_ + h];   // uniform s_loads

    __syncthreads();   // compiler drains vmcnt before s_barrier -> ledger = 0

    const uint32_t gbl = (uint32_t)grp << 4;
    const int n0 = P + wave * 16 + sub;        // positions n0 + {0,4,8,12}

    // shared A regs + named B ping-pong + carried softmax state
    f32x4 qr;
    f32x4 kr[7];
    f32x4 vrA[7], vrB[7], vxA, vxB;
    f32x2 ypA, ypB, zlA, zlB;
    float eA[J], eB[J], sumA, sumB;
    float p_[J];

    // ---- j = 0 ----
    ISSUEA(n0);
    VMWAIT(0);
    DOTP(n0);
    ISSUEB(n0, vrA, vxA, ypA, zlA);
    ISSUEA(n0 + 4);
    SOFTMAXE(n0, eA, sumA);
    // no epilogue yet

    // ---- j = 1 ----
    VMWAIT(0);                 // B(0)10 + A(1)8 outstanding; all needed
    DOTP(n0 + 4);
    ISSUEB(n0 + 4, vrB, vxB, ypB, zlB);
    ISSUEA(n0 + 8);
    SOFTMAXE(n0 + 4, eB, sumB);
    EPILOGUE(n0, vrA, vxA, ypA, zlA, eA, sumA);        // store(0)

    // ---- j = 2 ----
    VMWAIT(1);                 // leave store(0); forces B(1)+A(2)
    DOTP(n0 + 8);
    ISSUEB(n0 + 8, vrA, vxA, ypA, zlA);
    ISSUEA(n0 + 12);
    SOFTMAXE(n0 + 8, eA, sumA);
    EPILOGUE(n0 + 4, vrB, vxB, ypB, zlB, eB, sumB);    // store(1)

    // ---- j = 3 ----
    VMWAIT(1);                 // leave store(1); forces B(2)+A(3)
    DOTP(n0 + 12);
    ISSUEB(n0 + 12, vrB, vxB, ypB, zlB);
    SOFTMAXE(n0 + 12, eB, sumB);
    EPILOGUE(n0 + 8, vrA, vxA, ypA, zlA, eA, sumA);    // store(2)

    // ---- drain ----
    VMWAIT(1);                 // leave store(2); forces B(3)
    EPILOGUE(n0 + 12, vrB, vxB, ypB, zlB, eB, sumB);   // store(3)
}

} // namespace

extern "C" void kernel_launch(void* const* d_in, const int* in_sizes, int n_in,
                              void* d_out, int out_size, void* d_ws, size_t ws_size,
                              hipStream_t stream) {
    const float* q          = (const float*)d_in[0];
    const float* k          = (const float*)d_in[1];
    const float* v          = (const float*)d_in[2];
    const float* pb         = (const float*)d_in[3];
    const float* se         = (const float*)d_in[4];
    const float* phase_base = (const float*)d_in[5];
    const float* phase_gain = (const float*)d_in[6];
    const float* y_pre      = (const float*)d_in[7];
    const float* z_pre      = (const float*)d_in[8];
    float* out              = (float*)d_out;

    const int positions = B_ * H_ * N_;          // 131072
    const int blocks    = positions / T_;        // 2048 blocks, 64 pos each
    dsqg_kernel<<<blocks, 256, 0, stream>>>(q, k, v, pb, se, phase_base,
                                            phase_gain, y_pre, z_pre, out);
}